// Round 5
// baseline (580.521 us; speedup 1.0000x reference)
//
#include <hip/hip_runtime.h>
#include <hip/hip_bf16.h>

#define B_ 16
#define C_ 512
#define K_ 64
#define N_ 4096   // H*W
#define LDA 40    // padded LDS stride for reg-staged kernels (zfused/mugemm/recon)

typedef unsigned short ushort_t;
typedef __attribute__((ext_vector_type(8))) short s16x8;
typedef __attribute__((ext_vector_type(4))) short s16x4;
typedef __attribute__((ext_vector_type(4))) float f32x4;

__device__ inline ushort_t f2bf(float f) {            // RNE
    unsigned int u = __builtin_bit_cast(unsigned int, f);
    u = (u + 0x7FFFu + ((u >> 16) & 1u)) >> 16;
    return (ushort_t)u;
}
__device__ inline ushort_t f2bf_fast(float f) {       // round-half-up (bulk staging)
    unsigned int u = __builtin_bit_cast(unsigned int, f);
    return (ushort_t)((u + 0x8000u) >> 16);
}
__device__ inline float bf2f(ushort_t h) {
    unsigned int u = ((unsigned int)h) << 16;
    return __builtin_bit_cast(float, u);
}

// async global->LDS 16B copy (dest = wave-uniform base + lane*16)
__device__ inline void gload16(const ushort_t* g, ushort_t* l) {
    __builtin_amdgcn_global_load_lds(
        (const __attribute__((address_space(1))) void*)g,
        (__attribute__((address_space(3))) void*)l, 16, 0, 0);
}

// Stage R x 32 bf16 tile (row-major, contraction contiguous) into padded LDS.
template<int R>
__device__ inline void stage_tile(ushort_t* lds, const ushort_t* g, int gstride) {
    const int t = threadIdx.x;
    #pragma unroll
    for (int l = 0; l < R / 64; ++l) {
        int ch = t + l * 256;
        int row = ch >> 2, seg = ch & 3;
        s16x8 v = *(const s16x8*)(g + (size_t)row * gstride + seg * 8);
        *(s16x8*)(lds + row * LDA + seg * 8) = v;
    }
}

// ============================================================================
// cvt W1,W2 -> bf16, PRE-SWIZZLED for global_load_lds consumers:
// value-octet cg of each 32-col block stored at granule cg ^ ((o>>1)&3)
// ============================================================================
__global__ __launch_bounds__(256)
void cvtW_kernel(const float* __restrict__ W1, const float* __restrict__ W2,
                 ushort_t* __restrict__ W1b, ushort_t* __restrict__ W2b)
{
    int idx = blockIdx.x * 256 + threadIdx.x;   // 0..65535, 8 floats each
    const float* s; ushort_t* d; int off;
    if (idx < 32768) { s = W1; d = W1b; off = idx * 8; }
    else             { s = W2; d = W2b; off = (idx - 32768) * 8; }
    float4 a = *(const float4*)(s + off);
    float4 b = *(const float4*)(s + off + 4);
    s16x8 v;
    v[0] = (short)f2bf(a.x); v[1] = (short)f2bf(a.y);
    v[2] = (short)f2bf(a.z); v[3] = (short)f2bf(a.w);
    v[4] = (short)f2bf(b.x); v[5] = (short)f2bf(b.y);
    v[6] = (short)f2bf(b.z); v[7] = (short)f2bf(b.w);
    int o = off >> 9, c = off & 511;            // c is octet-aligned
    int dst = o * C_ + (c & ~31) + 8 * (((c >> 3) & 3) ^ ((o >> 1) & 3));
    *(s16x8*)(d + dst) = v;
}

// ============================================================================
// initmu: mu0 fp32 [c][k] -> mu_t bf16 [k][c]  (unswizzled; reg-staged consumer)
// ============================================================================
__global__ __launch_bounds__(256)
void initmu_kernel(const float* __restrict__ mu0, ushort_t* __restrict__ mu_t)
{
    int idx = blockIdx.x * 256 + threadIdx.x;   // c = idx>>6, k = idx&63
    float v = mu0[idx];
    mu_t[(idx & 63) * C_ + (idx >> 6)] = f2bf(v);
}

// ============================================================================
// xcvt: x fp32 [b][c][n] -> xbt bf16 [b][n][c], PRE-SWIZZLED (octet ^ (n>>1)&3)
// 64x64 tiles via LDS; 4x4 register transpose (no dynamic indexing)
// ============================================================================
__global__ __launch_bounds__(256)
void xcvt_kernel(const float* __restrict__ x, ushort_t* __restrict__ xbt)
{
    __shared__ __align__(16) ushort_t lds[64 * 72];
    const int n0 = blockIdx.x * 64;
    const int c0 = blockIdx.y * 64;
    const int b  = blockIdx.z;
    const int t  = threadIdx.x;
    const int cq = t >> 4, nq = t & 15;    // 4-wide c / n quads
    const float* src = x + ((size_t)b * C_ + c0 + cq * 4) * N_ + n0 + nq * 4;
    float4 f0 = *(const float4*)(src);
    float4 f1 = *(const float4*)(src + N_);
    float4 f2 = *(const float4*)(src + 2 * N_);
    float4 f3 = *(const float4*)(src + 3 * N_);
    ushort_t* ld = lds + (nq * 4) * 72 + cq * 4;
    s16x4 v;
    v[0] = (short)f2bf_fast(f0.x); v[1] = (short)f2bf_fast(f1.x);
    v[2] = (short)f2bf_fast(f2.x); v[3] = (short)f2bf_fast(f3.x);
    *(s16x4*)(ld) = v;
    v[0] = (short)f2bf_fast(f0.y); v[1] = (short)f2bf_fast(f1.y);
    v[2] = (short)f2bf_fast(f2.y); v[3] = (short)f2bf_fast(f3.y);
    *(s16x4*)(ld + 72) = v;
    v[0] = (short)f2bf_fast(f0.z); v[1] = (short)f2bf_fast(f1.z);
    v[2] = (short)f2bf_fast(f2.z); v[3] = (short)f2bf_fast(f3.z);
    *(s16x4*)(ld + 144) = v;
    v[0] = (short)f2bf_fast(f0.w); v[1] = (short)f2bf_fast(f1.w);
    v[2] = (short)f2bf_fast(f2.w); v[3] = (short)f2bf_fast(f3.w);
    *(s16x4*)(ld + 216) = v;
    __syncthreads();
    ushort_t* dst = xbt + ((size_t)b * N_ + n0) * C_ + c0;
    #pragma unroll
    for (int i = 0; i < 2; ++i) {
        int ch = t + 256 * i;
        int row = ch >> 3, seg = ch & 7;           // n-local row, c octet
        s16x8 w = *(const s16x8*)&lds[row * 72 + seg * 8];
        int cc = (seg >> 2) * 32 + 8 * ((seg & 3) ^ ((row >> 1) & 3));
        *(s16x8*)(dst + (size_t)row * C_ + cc) = w;
    }
}

// ============================================================================
// conv1: xf[b][o][n] bf16 = sum_c W1[o,c]*x[b,c,n] + b1[o]; also xft [n][o].
// Pure-bf16 m97-style: A=W1b (swz), B=xbt (swz) via global_load_lds, BK=32.
// grid (32, 4, 16), 256 thr, 4 waves (2x2), wave 64x64
// ============================================================================
__global__ __launch_bounds__(256)
void conv1_mfma(const ushort_t* __restrict__ W1b, const ushort_t* __restrict__ xbt,
                const float* __restrict__ b1, ushort_t* __restrict__ xf,
                ushort_t* __restrict__ xft)
{
    __shared__ __align__(16) ushort_t As[128 * 32];
    __shared__ __align__(16) ushort_t Bs[128 * 32];
    const int n0 = blockIdx.x * 128;
    const int o0 = blockIdx.y * 128;
    const int b  = blockIdx.z;
    const int t  = threadIdx.x;
    const int wid = t >> 6, lane = t & 63;
    const int wm = wid >> 1, wn = wid & 1;
    const int l15 = lane & 15, q = lane >> 4;
    const int gsw = (q ^ ((l15 >> 1) & 3)) * 8;    // swizzled fragment granule

    const ushort_t* gA = W1b + (size_t)o0 * C_;
    const ushort_t* gB = xbt + ((size_t)b * N_ + n0) * C_;
    const size_t choff  = (size_t)(t >> 2) * C_ + (t & 3) * 8;  // chunk t
    const size_t choff2 = choff + (size_t)64 * C_;              // chunk t+256

    int aoff[4], boff[4];
    #pragma unroll
    for (int m = 0; m < 4; ++m) aoff[m] = (wm * 64 + m * 16 + l15) * 32 + gsw;
    #pragma unroll
    for (int n = 0; n < 4; ++n) boff[n] = (wn * 64 + n * 16 + l15) * 32 + gsw;

    f32x4 acc[4][4] = {};

    for (int c0 = 0; c0 < C_; c0 += 32) {
        __syncthreads();
        gload16(gA + choff  + c0, &As[t * 8]);
        gload16(gA + choff2 + c0, &As[t * 8 + 2048]);
        gload16(gB + choff  + c0, &Bs[t * 8]);
        gload16(gB + choff2 + c0, &Bs[t * 8 + 2048]);
        __syncthreads();
        s16x8 af[4], bf[4];
        #pragma unroll
        for (int m = 0; m < 4; ++m) af[m] = *(const s16x8*)&As[aoff[m]];
        #pragma unroll
        for (int n = 0; n < 4; ++n) bf[n] = *(const s16x8*)&Bs[boff[n]];
        #pragma unroll
        for (int m = 0; m < 4; ++m)
            #pragma unroll
            for (int n = 0; n < 4; ++n)
                acc[m][n] = __builtin_amdgcn_mfma_f32_16x16x32_bf16(af[m], bf[n], acc[m][n], 0, 0, 0);
    }

    ushort_t* xfB  = xf  + (size_t)b * C_ * N_;
    ushort_t* xftB = xft + (size_t)b * N_ * C_;
    #pragma unroll
    for (int m = 0; m < 4; ++m) {
        int obase = o0 + wm * 64 + m * 16 + 4 * q;
        float bv[4];
        #pragma unroll
        for (int r = 0; r < 4; ++r) bv[r] = b1[obase + r];
        #pragma unroll
        for (int n = 0; n < 4; ++n) {
            int nn = n0 + wn * 64 + n * 16 + l15;
            s16x4 pk;
            #pragma unroll
            for (int r = 0; r < 4; ++r) {
                ushort_t h = f2bf(acc[m][n][r] + bv[r]);
                pk[r] = (short)h;
                xfB[(size_t)(obase + r) * N_ + nn] = h;
            }
            *(s16x4*)&xftB[(size_t)nn * C_ + obase] = pk;
        }
    }
}

// ============================================================================
// zfused: z GEMM + column softmax/blend + colsum + dual-layout write (r4 as-is)
// ============================================================================
__global__ __launch_bounds__(256)
void zfused_mfma(const ushort_t* __restrict__ mu_t, const ushort_t* __restrict__ xft,
                 ushort_t* __restrict__ zst, ushort_t* __restrict__ zs,
                 float* __restrict__ cs, int mustride)
{
    __shared__ __align__(16) char pool[64 * 133 * 4 + 64 * 132 * 2 + 128 * 2 * 4];
    float*    zt  = (float*)pool;                              // [64][133] fp32 z
    ushort_t* zb  = (ushort_t*)(pool + 64 * 133 * 4);          // [64][132] bf16 e
    float*    csb = (float*)(pool + 64 * 133 * 4 + 64 * 132 * 2); // [128][2]
    ushort_t* As  = (ushort_t*)pool;                           // loop-time alias
    ushort_t* Bs  = (ushort_t*)(pool + 64 * LDA * 2);

    const int n0 = blockIdx.x * 128;
    const int b  = blockIdx.y;
    const int t  = threadIdx.x;
    const int wid = t >> 6, lane = t & 63;
    const int wm = wid >> 1, wn = wid & 1;
    const int l15 = lane & 15, q = lane >> 4;

    const ushort_t* gA = mu_t + (size_t)b * mustride;
    const ushort_t* gB = xft + (size_t)b * N_ * C_ + (size_t)n0 * C_;

    f32x4 acc[2][4] = {};

    for (int c0 = 0; c0 < C_; c0 += 32) {
        __syncthreads();
        stage_tile<64>(As, gA + c0, C_);
        stage_tile<128>(Bs, gB + c0, C_);
        __syncthreads();
        s16x8 af[2], bf[4];
        #pragma unroll
        for (int m = 0; m < 2; ++m)
            af[m] = *(const s16x8*)&As[(wm * 32 + m * 16 + l15) * LDA + q * 8];
        #pragma unroll
        for (int n = 0; n < 4; ++n)
            bf[n] = *(const s16x8*)&Bs[(wn * 64 + n * 16 + l15) * LDA + q * 8];
        #pragma unroll
        for (int m = 0; m < 2; ++m)
            #pragma unroll
            for (int n = 0; n < 4; ++n)
                acc[m][n] = __builtin_amdgcn_mfma_f32_16x16x32_bf16(af[m], bf[n], acc[m][n], 0, 0, 0);
    }

    __syncthreads();   // As/Bs dead; pool becomes zt/zb/csb
    #pragma unroll
    for (int m = 0; m < 2; ++m) {
        int kbase = wm * 32 + m * 16 + 4 * q;
        #pragma unroll
        for (int n = 0; n < 4; ++n) {
            int nl = wn * 64 + n * 16 + l15;
            #pragma unroll
            for (int r = 0; r < 4; ++r)
                zt[(kbase + r) * 133 + nl] = acc[m][n][r];
        }
    }
    __syncthreads();
    if (t < 128) {
        const float* col = zt + t;
        float mx = -1e30f, sq = 0.f;
        #pragma unroll
        for (int k = 0; k < K_; ++k) {
            float v = col[k * 133];
            mx = fmaxf(mx, v);
            sq += v * v;
        }
        float se = 0.f;
        #pragma unroll
        for (int k = 0; k < K_; ++k) {
            float e = __expf(col[k * 133] - mx);
            se += e;
            zb[k * 132 + t] = f2bf(e);
        }
        csb[t * 2]     = 0.5f / se;
        csb[t * 2 + 1] = 0.5f * 64.f / (63.f + 2.f * sqrtf(sq));
    }
    __syncthreads();
    ushort_t* zstB = zst + (size_t)b * K_ * N_;
    #pragma unroll
    for (int i = 0; i < 4; ++i) {
        int ch = t + 256 * i;
        int k = ch >> 4, seg = ch & 15;
        s16x8 e8 = *(const s16x8*)&zb[k * 132 + seg * 8];
        s16x8 o8;
        float sum = 0.f;
        #pragma unroll
        for (int j = 0; j < 8; ++j) {
            int nl = seg * 8 + j;
            float v = fmaf(bf2f((ushort_t)e8[j]), csb[nl * 2], csb[nl * 2 + 1]);
            sum += v;
            o8[j] = (short)f2bf(v);
        }
        *(s16x8*)&zstB[(size_t)k * N_ + n0 + seg * 8] = o8;
        #pragma unroll
        for (int off = 1; off < 16; off <<= 1) sum += __shfl_xor(sum, off);
        if ((t & 15) == 0) atomicAdd(&cs[b * K_ + k], sum);
    }
    ushort_t* zsB = zs + (size_t)b * N_ * K_;
    #pragma unroll
    for (int i = 0; i < 4; ++i) {
        int ch = t + 256 * i;
        int nl = ch >> 3, kseg = ch & 7;
        float sc = csb[nl * 2], bl = csb[nl * 2 + 1];
        s16x8 o8;
        #pragma unroll
        for (int j = 0; j < 8; ++j) {
            int j2 = (j + nl) & 7;
            float v = fmaf(bf2f(zb[(kseg * 8 + j2) * 132 + nl]), sc, bl);
            o8[j2] = (short)f2bf(v);
        }
        *(s16x8*)&zsB[(size_t)(n0 + nl) * K_ + kseg * 8] = o8;
    }
}

// ============================================================================
// mugemm: macc[b][k][c] fp32 (atomic) += (1/(1e-6+cs[k]))*sum_n z[k,n]*xf[c,n]
// (r4 as-is)
// ============================================================================
__global__ __launch_bounds__(256)
void mugemm_mfma(const ushort_t* __restrict__ zst, const ushort_t* __restrict__ xf,
                 const float* __restrict__ cs, float* __restrict__ macc)
{
    __shared__ __align__(16) ushort_t As[64 * LDA];
    __shared__ __align__(16) ushort_t Bs[128 * LDA];
    const int ns = blockIdx.x * 512;
    const int c0 = blockIdx.y * 128;
    const int b  = blockIdx.z;
    const int t  = threadIdx.x;
    const int wid = t >> 6, lane = t & 63;
    const int wm = wid >> 1, wn = wid & 1;
    const int l15 = lane & 15, q = lane >> 4;

    const ushort_t* gA = zst + (size_t)b * K_ * N_ + ns;
    const ushort_t* gB = xf + (size_t)b * C_ * N_ + (size_t)c0 * N_ + ns;

    f32x4 acc[2][4] = {};

    for (int nn0 = 0; nn0 < 512; nn0 += 32) {
        __syncthreads();
        stage_tile<64>(As, gA + nn0, N_);
        stage_tile<128>(Bs, gB + nn0, N_);
        __syncthreads();
        s16x8 af[2], bf[4];
        #pragma unroll
        for (int m = 0; m < 2; ++m)
            af[m] = *(const s16x8*)&As[(wm * 32 + m * 16 + l15) * LDA + q * 8];
        #pragma unroll
        for (int n = 0; n < 4; ++n)
            bf[n] = *(const s16x8*)&Bs[(wn * 64 + n * 16 + l15) * LDA + q * 8];
        #pragma unroll
        for (int m = 0; m < 2; ++m)
            #pragma unroll
            for (int n = 0; n < 4; ++n)
                acc[m][n] = __builtin_amdgcn_mfma_f32_16x16x32_bf16(af[m], bf[n], acc[m][n], 0, 0, 0);
    }

    float* mB = macc + (size_t)b * K_ * C_;
    #pragma unroll
    for (int m = 0; m < 2; ++m) {
        int kbase = wm * 32 + m * 16 + 4 * q;
        float ic[4];
        #pragma unroll
        for (int r = 0; r < 4; ++r) ic[r] = 1.f / (1e-6f + cs[b * K_ + kbase + r]);
        #pragma unroll
        for (int n = 0; n < 4; ++n) {
            int cc = c0 + wn * 64 + n * 16 + l15;
            #pragma unroll
            for (int r = 0; r < 4; ++r)
                atomicAdd(&mB[(size_t)(kbase + r) * C_ + cc], acc[m][n][r] * ic[r]);
        }
    }
}

// ============================================================================
// l2norm over c (r4 as-is)
// ============================================================================
__global__ __launch_bounds__(256)
void l2norm_t(const float* __restrict__ macc, ushort_t* __restrict__ mu_t,
              ushort_t* __restrict__ mu_b, float* __restrict__ mu_out,
              float* __restrict__ theta_out)
{
    int wid  = blockIdx.x * 4 + (threadIdx.x >> 6);
    int lane = threadIdx.x & 63;
    int b = wid >> 6, k = wid & 63;
    const float* src = macc + (size_t)b * K_ * C_ + (size_t)k * C_;
    float v[8], s = 0.f;
    #pragma unroll
    for (int i = 0; i < 8; ++i) { v[i] = src[lane + i * 64]; s += v[i] * v[i]; }
    #pragma unroll
    for (int off = 32; off > 0; off >>= 1) s += __shfl_xor(s, off);
    float inv = 1.f / (1e-6f + sqrtf(s));
    ushort_t* mt = mu_t + (size_t)b * K_ * C_ + (size_t)k * C_;
    ushort_t* mb = mu_b + (size_t)b * C_ * K_ + k;
    float*    mo = mu_out + (size_t)b * C_ * K_ + k;
    #pragma unroll
    for (int i = 0; i < 8; ++i) {
        int c = lane + i * 64;
        float val = v[i] * inv;
        mt[c] = f2bf(val);
        mb[(size_t)c * K_] = f2bf(val);
        mo[(size_t)c * K_] = val;
    }
    if (wid == 0 && lane == 0) *theta_out = 45.0f;
}

// ============================================================================
// recon: xrt[n][c] bf16 = relu(sum_k mu[c,k]*z[n,k]) — xrt stores PRE-SWIZZLED
// for conv2's global_load_lds path. Loop unchanged (reg-staged).
// ============================================================================
__global__ __launch_bounds__(256)
void recon_mfma(const ushort_t* __restrict__ mu_b, const ushort_t* __restrict__ zs,
                ushort_t* __restrict__ xrt)
{
    __shared__ __align__(16) ushort_t As[128 * LDA];
    __shared__ __align__(16) ushort_t Bs[128 * LDA];
    const int n0 = blockIdx.x * 128;
    const int c0 = blockIdx.y * 128;
    const int b  = blockIdx.z;
    const int t  = threadIdx.x;
    const int wid = t >> 6, lane = t & 63;
    const int wm = wid >> 1, wn = wid & 1;
    const int l15 = lane & 15, q = lane >> 4;

    const ushort_t* gA = mu_b + (size_t)b * C_ * K_ + (size_t)c0 * K_;
    const ushort_t* gB = zs + (size_t)b * N_ * K_ + (size_t)n0 * K_;

    f32x4 acc[4][4] = {};

    for (int k0 = 0; k0 < K_; k0 += 32) {
        __syncthreads();
        stage_tile<128>(As, gA + k0, K_);
        stage_tile<128>(Bs, gB + k0, K_);
        __syncthreads();
        s16x8 af[4], bf[4];
        #pragma unroll
        for (int m = 0; m < 4; ++m)
            af[m] = *(const s16x8*)&As[(wm * 64 + m * 16 + l15) * LDA + q * 8];
        #pragma unroll
        for (int n = 0; n < 4; ++n)
            bf[n] = *(const s16x8*)&Bs[(wn * 64 + n * 16 + l15) * LDA + q * 8];
        #pragma unroll
        for (int m = 0; m < 4; ++m)
            #pragma unroll
            for (int n = 0; n < 4; ++n)
                acc[m][n] = __builtin_amdgcn_mfma_f32_16x16x32_bf16(af[m], bf[n], acc[m][n], 0, 0, 0);
    }

    ushort_t* xB = xrt + (size_t)b * N_ * C_;
    const int swn = (l15 >> 1) & 3;     // ((nn)>>1)&3, lane-dependent only
    #pragma unroll
    for (int m = 0; m < 4; ++m) {
        int cbase = c0 + wm * 64 + m * 16 + 4 * q;
        int cswz  = (cbase & ~31) + 8 * (((cbase >> 3) & 3) ^ swn) + (cbase & 7);
        #pragma unroll
        for (int n = 0; n < 4; ++n) {
            int nn = n0 + wn * 64 + n * 16 + l15;
            s16x4 pk;
            #pragma unroll
            for (int r = 0; r < 4; ++r)
                pk[r] = (short)f2bf(fmaxf(acc[m][n][r], 0.f));
            *(s16x4*)&xB[(size_t)nn * C_ + cswz] = pk;
        }
    }
}

// ============================================================================
// conv2: y[b][o][n] fp32 = sum_c W2[o,c]*xr[c,n]; pure-bf16 m97-style loop
// (A=W2b swz, B=xrt swz via global_load_lds). Fused BN stats epilogue (r4).
// ============================================================================
__global__ __launch_bounds__(256)
void conv2_mfma(const ushort_t* __restrict__ W2b, const ushort_t* __restrict__ xrt,
                float* __restrict__ y, float* __restrict__ ysum, float* __restrict__ ysq)
{
    __shared__ __align__(16) ushort_t As[128 * 32];
    __shared__ __align__(16) ushort_t Bs[128 * 32];
    __shared__ float sums[128][2];
    const int n0 = blockIdx.x * 128;
    const int o0 = blockIdx.y * 128;
    const int b  = blockIdx.z;
    const int t  = threadIdx.x;
    const int wid = t >> 6, lane = t & 63;
    const int wm = wid >> 1, wn = wid & 1;
    const int l15 = lane & 15, q = lane >> 4;
    const int gsw = (q ^ ((l15 >> 1) & 3)) * 8;

    const ushort_t* gA = W2b + (size_t)o0 * C_;
    const ushort_t* gB = xrt + ((size_t)b * N_ + n0) * C_;
    const size_t choff  = (size_t)(t >> 2) * C_ + (t & 3) * 8;
    const size_t choff2 = choff + (size_t)64 * C_;

    int aoff[4], boff[4];
    #pragma unroll
    for (int m = 0; m < 4; ++m) aoff[m] = (wm * 64 + m * 16 + l15) * 32 + gsw;
    #pragma unroll
    for (int n = 0; n < 4; ++n) boff[n] = (wn * 64 + n * 16 + l15) * 32 + gsw;

    f32x4 acc[4][4] = {};

    for (int c0 = 0; c0 < C_; c0 += 32) {
        __syncthreads();
        gload16(gA + choff  + c0, &As[t * 8]);
        gload16(gA + choff2 + c0, &As[t * 8 + 2048]);
        gload16(gB + choff  + c0, &Bs[t * 8]);
        gload16(gB + choff2 + c0, &Bs[t * 8 + 2048]);
        __syncthreads();
        s16x8 af[4], bf[4];
        #pragma unroll
        for (int m = 0; m < 4; ++m) af[m] = *(const s16x8*)&As[aoff[m]];
        #pragma unroll
        for (int n = 0; n < 4; ++n) bf[n] = *(const s16x8*)&Bs[boff[n]];
        #pragma unroll
        for (int m = 0; m < 4; ++m)
            #pragma unroll
            for (int n = 0; n < 4; ++n)
                acc[m][n] = __builtin_amdgcn_mfma_f32_16x16x32_bf16(af[m], bf[n], acc[m][n], 0, 0, 0);
    }

    float* yB = y + (size_t)b * C_ * N_;
    float ps[4][4], pq[4][4];
    #pragma unroll
    for (int m = 0; m < 4; ++m) {
        int obase = o0 + wm * 64 + m * 16 + 4 * q;
        #pragma unroll
        for (int r = 0; r < 4; ++r) { ps[m][r] = 0.f; pq[m][r] = 0.f; }
        #pragma unroll
        for (int n = 0; n < 4; ++n) {
            int nn = n0 + wn * 64 + n * 16 + l15;
            #pragma unroll
            for (int r = 0; r < 4; ++r) {
                float v = acc[m][n][r];
                yB[(size_t)(obase + r) * N_ + nn] = v;
                ps[m][r] += v;
                pq[m][r] = fmaf(v, v, pq[m][r]);
            }
        }
    }
    #pragma unroll
    for (int m = 0; m < 4; ++m)
        #pragma unroll
        for (int r = 0; r < 4; ++r)
            #pragma unroll
            for (int off = 1; off < 16; off <<= 1) {
                ps[m][r] += __shfl_xor(ps[m][r], off);
                pq[m][r] += __shfl_xor(pq[m][r], off);
            }
    __syncthreads();
    if (l15 == 0 && wn == 0) {
        #pragma unroll
        for (int m = 0; m < 4; ++m)
            #pragma unroll
            for (int r = 0; r < 4; ++r) {
                int ol = wm * 64 + m * 16 + 4 * q + r;
                sums[ol][0] = ps[m][r];
                sums[ol][1] = pq[m][r];
            }
    }
    __syncthreads();
    if (l15 == 0 && wn == 1) {
        #pragma unroll
        for (int m = 0; m < 4; ++m)
            #pragma unroll
            for (int r = 0; r < 4; ++r) {
                int ol = wm * 64 + m * 16 + 4 * q + r;
                sums[ol][0] += ps[m][r];
                sums[ol][1] += pq[m][r];
            }
    }
    __syncthreads();
    if (t < 128) {
        atomicAdd(&ysum[o0 + t], sums[t][0]);
        atomicAdd(&ysq[o0 + t],  sums[t][1]);
    }
}

// ============================================================================
// final: out = relu(y*scale + shift + x), in place (r4 as-is)
// ============================================================================
__global__ __launch_bounds__(256)
void bnout_kernel(float* __restrict__ y, const float* __restrict__ x,
                  const float* __restrict__ gamma, const float* __restrict__ beta,
                  const float* __restrict__ ysum, const float* __restrict__ ysq)
{
    size_t i = (size_t)blockIdx.x * 256 + threadIdx.x;   // float4 index
    float4 vy = ((float4*)y)[i];
    float4 vx = ((const float4*)x)[i];
    int o = (int)((i >> 10) & (C_ - 1));
    const float inv_n = 1.f / (float)(B_ * N_);
    float mean = ysum[o] * inv_n;
    float var  = ysq[o] * inv_n - mean * mean;
    float istd = rsqrtf(var + 1e-5f);
    float sc = gamma[o] * istd;
    float sh = beta[o] - sc * mean;
    float4 r;
    r.x = fmaxf(fmaf(vy.x, sc, sh) + vx.x, 0.f);
    r.y = fmaxf(fmaf(vy.y, sc, sh) + vx.y, 0.f);
    r.z = fmaxf(fmaf(vy.z, sc, sh) + vx.z, 0.f);
    r.w = fmaxf(fmaf(vy.w, sc, sh) + vx.w, 0.f);
    ((float4*)y)[i] = r;
}

// ============================================================================
extern "C" void kernel_launch(void* const* d_in, const int* in_sizes, int n_in,
                              void* d_out, int out_size, void* d_ws, size_t ws_size,
                              hipStream_t stream)
{
    const float* x     = (const float*)d_in[0];
    const float* W1    = (const float*)d_in[1];
    const float* b1    = (const float*)d_in[2];
    const float* W2    = (const float*)d_in[3];
    const float* gamma = (const float*)d_in[4];
    const float* beta  = (const float*)d_in[5];
    const float* mu0   = (const float*)d_in[6];

    // workspace layout (~139.5 MB)
    char* w = (char*)d_ws;
    ushort_t* xf   = (ushort_t*)w;  w += (size_t)B_ * C_ * N_ * 2;   // 67.1 MB (later xrt)
    ushort_t* xft  = (ushort_t*)w;  w += (size_t)B_ * N_ * C_ * 2;   // 67.1 MB
    ushort_t* W1b  = (ushort_t*)w;  w += (size_t)C_ * C_ * 2;
    ushort_t* W2b  = (ushort_t*)w;  w += (size_t)C_ * C_ * 2;
    ushort_t* mu_t = (ushort_t*)w;  w += (size_t)B_ * K_ * C_ * 2;
    ushort_t* mu_b = (ushort_t*)w;  w += (size_t)B_ * C_ * K_ * 2;
    float* cs      = (float*)w;     w += (size_t)B_ * K_ * 4;        // colsum accum
    float* macc    = (float*)w;     w += (size_t)B_ * K_ * C_ * 4;   // 2 MB
    float* ysum    = (float*)w;     w += C_ * 4;
    float* ysq     = (float*)w;     w += C_ * 4;

    ushort_t* xrt = xf;   // alias: xf dead after stage-2 mugemm

    float* y         = (float*)d_out;                    // conv2 out / final out
    float* mu_out    = (float*)d_out + (size_t)B_ * C_ * N_;
    float* theta_out = mu_out + (size_t)B_ * C_ * K_;
    // transient buffers inside the (dead-until-conv2) y region of d_out:
    ushort_t* xbt = (ushort_t*)d_out;                                 // 67.1 MB, dead after conv1
    ushort_t* zst = (ushort_t*)((char*)d_out + (size_t)80 * 1024 * 1024); // 8.4 MB
    ushort_t* zs  = (ushort_t*)((char*)d_out + (size_t)96 * 1024 * 1024); // 8.4 MB

    cvtW_kernel<<<256, 256, 0, stream>>>(W1, W2, W1b, W2b);
    initmu_kernel<<<128, 256, 0, stream>>>(mu0, mu_t);
    hipMemsetAsync(ysum, 0, 2 * C_ * 4, stream);

    xcvt_kernel<<<dim3(64, 8, 16), 256, 0, stream>>>(x, xbt);
    conv1_mfma<<<dim3(32, 4, 16), 256, 0, stream>>>(W1b, xbt, b1, xf, xft);

    for (int s = 0; s < 2; ++s) {
        hipMemsetAsync(cs, 0, (size_t)B_ * K_ * 4 + (size_t)B_ * K_ * C_ * 4, stream);
        zfused_mfma<<<dim3(32, 16), 256, 0, stream>>>(mu_t, xft, zst, zs, cs,
                                                      s == 0 ? 0 : K_ * C_);
        mugemm_mfma<<<dim3(8, 4, 16), 256, 0, stream>>>(zst, xf, cs, macc);
        l2norm_t<<<256, 256, 0, stream>>>(macc, mu_t, mu_b, mu_out, theta_out);
    }

    recon_mfma<<<dim3(32, 4, 16), 256, 0, stream>>>(mu_b, zs, xrt);
    conv2_mfma<<<dim3(32, 4, 16), 256, 0, stream>>>(W2b, xrt, y, ysum, ysq);
    bnout_kernel<<<dim3(B_ * C_ * N_ / 4 / 256), 256, 0, stream>>>(y, x, gamma, beta, ysum, ysq);
}